// Round 2
// baseline (100.206 us; speedup 1.0000x reference)
//
#include <hip/hip_runtime.h>
#include <hip/hip_fp16.h>

#define TT 256
#define DD 128
#define NEG -30000.0f

typedef __attribute__((ext_vector_type(4))) float f32x4;
typedef __attribute__((ext_vector_type(8))) _Float16 f16x8;
typedef unsigned int u32;
typedef __attribute__((ext_vector_type(4))) u32 u32x4;
typedef unsigned short u16;

__device__ __forceinline__ u16 tof16(float v) {
  return __builtin_bit_cast(u16, (_Float16)v);
}
__device__ __forceinline__ u32 pkf16(float lo, float hi) {
  return (u32)tof16(lo) | ((u32)tof16(hi) << 16);
}

// XOR swizzle on 16B chunks within a row: rows r and r+8 alias (2-way, free).
__device__ __forceinline__ int swz3(int row, int c) {
  return c ^ ((row ^ (row >> 3)) & 7);
}
__device__ __forceinline__ int offR256(int row, int c) {   // [*][128] f16 tile
  return (row << 8) | (swz3(row, c) << 4);
}
__device__ __forceinline__ int offR512(int row, int c) {   // [*][256] f16 tile
  return (row << 9) | (swz3(row, c) << 4);
}
__device__ __forceinline__ int offR256h(int row, int col) {
  return (row << 8) | (swz3(row, col >> 3) << 4) | ((col & 7) << 1);
}
__device__ __forceinline__ int offR512h(int row, int col) {
  return (row << 9) | (swz3(row, col >> 3) << 4) | ((col & 7) << 1);
}

__device__ __forceinline__ f32x4 mfma16(f16x8 a, f16x8 b, f32x4 c) {
  return __builtin_amdgcn_mfma_f32_16x16x32_f16(a, b, c, 0, 0, 0);
}

// ---------------- precompute: MT[d'][d] = M[d][d'] = sum_e Wq[e][d]Wk[e][d'];
// WvB = f16(Wv); m0[d'] = sum_e bq[e] Wk[e][d']
__global__ void precompute_k(const float* __restrict__ Wk, const float* __restrict__ Wq,
                             const float* __restrict__ bq, const float* __restrict__ Wv,
                             u16* __restrict__ MT, u16* __restrict__ WvB, float* __restrict__ m0) {
  int dp = blockIdx.x;
  int d  = threadIdx.x;
  float acc = 0.f;
  for (int e = 0; e < DD; ++e) acc = fmaf(Wq[e*DD + d], Wk[e*DD + dp], acc);
  MT[dp*DD + d] = tof16(acc);
  WvB[dp*DD + d] = tof16(Wv[dp*DD + d]);
  if (dp == 0) {
    float a0 = 0.f;
    for (int e = 0; e < DD; ++e) a0 = fmaf(bq[e], Wk[e*DD + d], a0);
    m0[d] = a0;
  }
}

// ---------------- per-q-subtile: S^T tiles = X·A^T, causal mask, softmax, P -> B-frags
template<int MAXT, int MAXC>
__device__ __forceinline__ void attn_sub(int qt, u32x4 (&pf)[MAXC], float& lsum,
                                         const char* bufX, const char* bufA,
                                         int l15, int g) {
  const int nkt = qt + 1;
  const int nch = (nkt + 1) >> 1;
  #pragma unroll
  for (int c = 0; c < MAXC; ++c) { u32x4 z = {0u,0u,0u,0u}; pf[c] = z; }
  f16x8 bA[4];
  #pragma unroll
  for (int kc = 0; kc < 4; ++kc)
    bA[kc] = *(const f16x8*)(bufA + offR256(qt*16 + l15, 4*kc + g));
  f32x4 sacc[MAXT];
  #pragma unroll
  for (int kt = 0; kt < MAXT; ++kt) { f32x4 z = {NEG, NEG, NEG, NEG}; sacc[kt] = z; }
  #pragma unroll
  for (int kt = 0; kt < MAXT; ++kt) {
    if (kt < nkt) {
      f32x4 acc = {0.f, 0.f, 0.f, 0.f};
      #pragma unroll
      for (int kc = 0; kc < 4; ++kc) {
        f16x8 aX = *(const f16x8*)(bufX + offR256(kt*16 + l15, 4*kc + g));
        acc = mfma16(aX, bA[kc], acc);
      }
      if (kt == nkt - 1) {            // diagonal tile: keep k_local <= q_local
        #pragma unroll
        for (int j = 0; j < 4; ++j)
          if (g*4 + j > l15) acc[j] = NEG;
      }
      sacc[kt] = acc;
    }
  }
  float mx = NEG;
  #pragma unroll
  for (int kt = 0; kt < MAXT; ++kt) if (kt < nkt) {
    #pragma unroll
    for (int j = 0; j < 4; ++j) mx = fmaxf(mx, sacc[kt][j]);
  }
  mx = fmaxf(mx, __shfl_xor(mx, 16));
  mx = fmaxf(mx, __shfl_xor(mx, 32));
  float sum = 0.f;
  #pragma unroll
  for (int kt = 0; kt < MAXT; ++kt) if (kt < nkt) {
    #pragma unroll
    for (int j = 0; j < 4; ++j) {
      float p = __expf(sacc[kt][j] - mx);
      sacc[kt][j] = p;
      sum += p;
    }
  }
  sum += __shfl_xor(sum, 16);
  sum += __shfl_xor(sum, 32);
  lsum = sum;
  // P^T regs (k=kt*16+g*4+j, q=l15) -> PV B-frag (lane needs P[c*32+g*8+j][l15])
  #pragma unroll
  for (int c = 0; c < MAXC; ++c) {
    if (c < nch) {
      u32 p00 = pkf16(sacc[2*c][0], sacc[2*c][1]);
      u32 p01 = pkf16(sacc[2*c][2], sacc[2*c][3]);
      u32 p10 = 0u, p11 = 0u;
      if (2*c + 1 < nkt) {
        p10 = pkf16(sacc[2*c+1][0], sacc[2*c+1][1]);
        p11 = pkf16(sacc[2*c+1][2], sacc[2*c+1][3]);
      }
      u32x4 w;
      #pragma unroll
      for (int wd = 0; wd < 4; ++wd) {
        int src = l15 + 16*((2*g + (wd >> 1)) & 3);
        u32 lo = (u32)__shfl((int)((wd & 1) ? p01 : p00), src, 64);
        u32 hi = (u32)__shfl((int)((wd & 1) ? p11 : p10), src, 64);
        w[wd] = (g >> 1) ? hi : lo;
      }
      pf[c] = w;
    }
  }
}

// ---------------- per-q-subtile epilogue: O^T = VT·P, normalize, +bv, store
template<int MAXC>
__device__ __forceinline__ void out_sub(int qt, const u32x4 (&pf)[MAXC], float lsum,
                                        const char* bufVT, const float* __restrict__ bvg,
                                        float* __restrict__ outb, int l15, int g) {
  const int nch = (qt + 2) >> 1;
  const float inv = 1.f / lsum;
  #pragma unroll
  for (int et = 0; et < 8; ++et) {
    f32x4 acc = {0.f, 0.f, 0.f, 0.f};
    #pragma unroll
    for (int c = 0; c < MAXC; ++c) {
      if (c < nch) {
        f16x8 aV = *(const f16x8*)(bufVT + offR512(et*16 + l15, 4*c + g));
        f16x8 pb = __builtin_bit_cast(f16x8, pf[c]);
        acc = mfma16(aV, pb, acc);
      }
    }
    const int q  = qt*16 + l15;
    const int e0 = et*16 + g*4;
    f32x4 bvv = *(const f32x4*)(bvg + e0);
    f32x4 o;
    #pragma unroll
    for (int j = 0; j < 4; ++j) o[j] = acc[j]*inv + bvv[j];
    *(f32x4*)(outb + q*DD + e0) = o;
  }
}

// ---------------- fused head kernel: 1 block per batch, 8 waves, 160KB LDS
__global__ __launch_bounds__(512, 2)
void head_fused(const float* __restrict__ x, const u16* __restrict__ MTg,
                const u16* __restrict__ Wvg, const float* __restrict__ m0g,
                const float* __restrict__ bvg, float* __restrict__ out) {
  extern __shared__ char lds[];
  char* bufX = lds;            // X [256][128] f16 swizzled (64 KB)
  char* bufA = lds + 65536;    // A [256][128] -> reused as VT [128][256] (64 KB)
  char* bufW = lds + 131072;   // MT then Wv [128][128] f16 swizzled (32 KB)

  const int tid  = threadIdx.x;
  const int wave = tid >> 6;
  const int lane = tid & 63;
  const int l15  = lane & 15;
  const int g    = lane >> 4;
  const int b    = blockIdx.x;
  const float* xb = x + (size_t)b * (TT*DD);

  // Phase 0: defensive zero-init of all LDS (cheap; makes any residual
  // uninit-read deterministic instead of NaN-capable garbage)
  {
    u32x4* p = (u32x4*)lds;
    #pragma unroll
    for (int i = 0; i < 20; ++i) { u32x4 z = {0u,0u,0u,0u}; p[tid + i*512] = z; }
  }
  __syncthreads();

  // Phase 1: stage X (f32->f16, swizzled) + MT
  #pragma unroll
  for (int i = 0; i < 8; ++i) {
    int chunk = tid + i*512;
    int row = chunk >> 4, c = chunk & 15;
    const float* p = xb + row*DD + c*8;
    f32x4 v0 = *(const f32x4*)p;
    f32x4 v1 = *(const f32x4*)(p + 4);
    u32x4 w;
    w[0] = pkf16(v0[0], v0[1]);
    w[1] = pkf16(v0[2], v0[3]);
    w[2] = pkf16(v1[0], v1[1]);
    w[3] = pkf16(v1[2], v1[3]);
    *(u32x4*)(bufX + offR256(row, c)) = w;
  }
  #pragma unroll
  for (int i = 0; i < 4; ++i) {
    int chunk = tid + i*512;
    int row = chunk >> 4, c = chunk & 15;
    u32x4 v = *(const u32x4*)((const char*)MTg + row*256 + c*16);
    *(u32x4*)(bufW + offR256(row, c)) = v;
  }
  __syncthreads();

  // Phase 2: A = X·MT^T(+m0) -> bufA   (A[q][d'] = sum_d X[q][d] M[d][d'] + m0[d'])
  #pragma unroll
  for (int s = 0; s < 2; ++s) {
    const int qt = 2*wave + s;
    f16x8 aX[4];
    #pragma unroll
    for (int kc = 0; kc < 4; ++kc)
      aX[kc] = *(const f16x8*)(bufX + offR256(qt*16 + l15, 4*kc + g));
    #pragma unroll
    for (int nt = 0; nt < 8; ++nt) {
      f32x4 acc = {0.f, 0.f, 0.f, 0.f};
      #pragma unroll
      for (int kc = 0; kc < 4; ++kc) {
        f16x8 bM = *(const f16x8*)(bufW + offR256(nt*16 + l15, 4*kc + g));
        acc = mfma16(aX[kc], bM, acc);
      }
      float m0v = m0g[nt*16 + l15];
      #pragma unroll
      for (int j = 0; j < 4; ++j)
        *(u16*)(bufA + offR256h(qt*16 + g*4 + j, nt*16 + l15)) = tof16(acc[j] + m0v);
    }
  }
  __syncthreads();

  // Phase 3: per-wave S^T + softmax + P-frags (wave w: q-tiles w and 15-w, balanced)
  u32x4 pf0[4]; u32x4 pf1[8];
  float ls0, ls1;
  attn_sub<8, 4>(wave,       pf0, ls0, bufX, bufA, l15, g);
  attn_sub<16, 8>(15 - wave, pf1, ls1, bufX, bufA, l15, g);
  __syncthreads();

  // Phase 4a: stage Wv over MT
  #pragma unroll
  for (int i = 0; i < 4; ++i) {
    int chunk = tid + i*512;
    int row = chunk >> 4, c = chunk & 15;
    u32x4 v = *(const u32x4*)((const char*)Wvg + row*256 + c*16);
    *(u32x4*)(bufW + offR256(row, c)) = v;
  }
  __syncthreads();

  // Phase 4b: VT = Wv·X^T -> bufA reused as [128][256]  (VT[e][k] = V[k][e] - bv)
  #pragma unroll
  for (int s = 0; s < 2; ++s) {
    const int kt = 2*wave + s;
    f16x8 bX[4];
    #pragma unroll
    for (int kc = 0; kc < 4; ++kc)
      bX[kc] = *(const f16x8*)(bufX + offR256(kt*16 + l15, 4*kc + g));
    #pragma unroll
    for (int et = 0; et < 8; ++et) {
      f32x4 acc = {0.f, 0.f, 0.f, 0.f};
      #pragma unroll
      for (int kc = 0; kc < 4; ++kc) {
        f16x8 aW = *(const f16x8*)(bufW + offR256(et*16 + l15, 4*kc + g));
        acc = mfma16(aW, bX[kc], acc);
      }
      #pragma unroll
      for (int j = 0; j < 4; ++j)
        *(u16*)(bufA + offR512h(et*16 + g*4 + j, kt*16 + l15)) = tof16(acc[j]);
    }
  }
  __syncthreads();

  // Phase 5: O = P·V / l + bv
  float* outb = out + (size_t)b * (TT*DD);
  out_sub<4>(wave,       pf0, ls0, bufA, bvg, outb, l15, g);
  out_sub<8>(15 - wave,  pf1, ls1, bufA, bvg, outb, l15, g);
}

extern "C" void kernel_launch(void* const* d_in, const int* in_sizes, int n_in,
                              void* d_out, int out_size, void* d_ws, size_t ws_size,
                              hipStream_t stream) {
  (void)in_sizes; (void)n_in; (void)out_size; (void)ws_size;
  const float* x  = (const float*)d_in[0];
  const float* Wk = (const float*)d_in[1];
  // d_in[2] = bk: contributes only per-q-row constants to scores -> dropped by softmax
  const float* Wq = (const float*)d_in[3];
  const float* bq = (const float*)d_in[4];
  const float* Wv = (const float*)d_in[5];
  const float* bv = (const float*)d_in[6];

  char* ws = (char*)d_ws;
  u16*   MT  = (u16*)ws;               // 32 KB
  u16*   WvB = (u16*)(ws + 32768);     // 32 KB
  float* m0  = (float*)(ws + 65536);   // 512 B

  (void)hipFuncSetAttribute((const void*)head_fused,
                            hipFuncAttributeMaxDynamicSharedMemorySize, 163840);

  precompute_k<<<128, 128, 0, stream>>>(Wk, Wq, bq, Wv, MT, WvB, m0);
  head_fused<<<512, 512, 163840, stream>>>(x, MT, WvB, m0, bv, (float*)d_out);
}